// Round 7
// baseline (477.872 us; speedup 1.0000x reference)
//
#include <hip/hip_runtime.h>
#include <math.h>

#define BTOT   32768
#define LAT    128
#define H      17
#define G4     68      // 4*H
#define TSTEPS 50

__device__ __forceinline__ float fsigmoid(float x) {
    float e = __expf(-x);
    return __fdividef(1.0f, 1.0f + e);
}
// overflow-safe tanh: |arg| can reach ~50, naive exp(2x) would overflow
__device__ __forceinline__ float ftanhf(float x) {
    float ax = fabsf(x);
    float e = __expf(-2.0f * ax);
    float t = __fdividef(1.0f - e, 1.0f + e);
    return copysignf(t, x);
}

// Round-6 redesign: THREAD-PER-ROW.
//  - 512 blocks x 64 threads (1 wave/block), row = blockIdx*64 + lane. Exact fit.
//  - All weight indices are compile-time constants -> wave-uniform addresses ->
//    compiler emits s_load (SGPR operands on v_fmac). No per-lane W traffic.
//    (R5/R6 evidence: per-lane W cannot be kept in VGPRs -- allocator banks it
//    into AGPRs and pays v_accvgpr_read per use; VGPR_Count=52 proved it.)
//  - h/c/xg live in THIS thread's VGPRs -> zero LDS, zero barriers, no exchange.
//  - opaque "+s" asm inside the T-loop defeats LICM on the 1156 loop-invariant
//    W_hh loads (hoisting them would need 1156 registers -> spill apocalypse).
__global__ __launch_bounds__(64, 1)
void lstm_rowwise(const float* __restrict__ x,
                  const float* __restrict__ W_h0, const float* __restrict__ b_h0,
                  const float* __restrict__ W_c0, const float* __restrict__ b_c0,
                  const float* __restrict__ W_ih, const float* __restrict__ W_hh,
                  const float* __restrict__ b_ih, const float* __restrict__ b_hh,
                  float* __restrict__ out)
{
    const int row = blockIdx.x * 64 + (threadIdx.x & 63);   // exact: 512*64 = 32768

    // ---- phase 1: acc[0..67]=x@W_ih^T, [68..84]=x@W_h0^T, [85..101]=x@W_c0^T ----
    float acc[102];
#pragma unroll
    for (int g = 0; g < 102; ++g) acc[g] = 0.0f;

    const float* xrow = x + (size_t)row * LAT;
    for (int kc = 0; kc < LAT / 4; ++kc) {        // dynamic loop, 32 iters
        const float4 xv = *(const float4*)(xrow + kc * 4);  // per-lane, line-sequential
#pragma unroll
        for (int g = 0; g < G4; ++g) {            // W reads: uniform -> s_load_dwordx4
            const float* wr = W_ih + g * LAT + kc * 4;
            acc[g] = fmaf(xv.x, wr[0], acc[g]);
            acc[g] = fmaf(xv.y, wr[1], acc[g]);
            acc[g] = fmaf(xv.z, wr[2], acc[g]);
            acc[g] = fmaf(xv.w, wr[3], acc[g]);
        }
#pragma unroll
        for (int g = 0; g < H; ++g) {
            const float* wr = W_h0 + g * LAT + kc * 4;
            acc[G4 + g] = fmaf(xv.x, wr[0], acc[G4 + g]);
            acc[G4 + g] = fmaf(xv.y, wr[1], acc[G4 + g]);
            acc[G4 + g] = fmaf(xv.z, wr[2], acc[G4 + g]);
            acc[G4 + g] = fmaf(xv.w, wr[3], acc[G4 + g]);
        }
#pragma unroll
        for (int g = 0; g < H; ++g) {
            const float* wr = W_c0 + g * LAT + kc * 4;
            acc[85 + g] = fmaf(xv.x, wr[0], acc[85 + g]);
            acc[85 + g] = fmaf(xv.y, wr[1], acc[85 + g]);
            acc[85 + g] = fmaf(xv.z, wr[2], acc[85 + g]);
            acc[85 + g] = fmaf(xv.w, wr[3], acc[85 + g]);
        }
    }

    float xg[G4], h[H], c[H];
#pragma unroll
    for (int g = 0; g < G4; ++g) xg[g] = acc[g] + b_ih[g] + b_hh[g];
#pragma unroll
    for (int e = 0; e < H; ++e) {
        h[e] = acc[G4 + e] + b_h0[e];
        c[e] = acc[85 + e] + b_c0[e];
    }

    // ---- phase 2: 50-step recurrence, all state in registers ----
    float* orow = out + (size_t)row * (TSTEPS * H);
    for (int tt = 0; tt < TSTEPS; ++tt) {
        int zoff = 0;
        asm volatile("" : "+s"(zoff));            // opaque 0: W_hh loads not hoistable
        const float* Wt = W_hh + zoff;            // still uniform -> s_load

        float hn[H];
#pragma unroll
        for (int e = 0; e < H; ++e) {
            float ai = xg[e], af = xg[H + e], ag = xg[2 * H + e], ao = xg[3 * H + e];
#pragma unroll
            for (int k = 0; k < H; ++k) {         // W rows e,17+e,34+e,51+e: contiguous 17 each
                ai = fmaf(Wt[(0 * H + e) * H + k], h[k], ai);
                af = fmaf(Wt[(1 * H + e) * H + k], h[k], af);
                ag = fmaf(Wt[(2 * H + e) * H + k], h[k], ag);
                ao = fmaf(Wt[(3 * H + e) * H + k], h[k], ao);
            }
            const float ig = fsigmoid(ai);
            const float fg = fsigmoid(af);
            const float gv = ftanhf(ag);
            const float og = fsigmoid(ao);
            c[e]  = fmaf(fg, c[e], ig * gv);
            hn[e] = og * ftanhf(c[e]);
            orow[tt * H + e] = hn[e];             // 68B contiguous per thread-step
        }
#pragma unroll
        for (int e = 0; e < H; ++e) h[e] = hn[e]; // old h used by all e above
    }
}

extern "C" void kernel_launch(void* const* d_in, const int* in_sizes, int n_in,
                              void* d_out, int out_size, void* d_ws, size_t ws_size,
                              hipStream_t stream)
{
    const float* x    = (const float*)d_in[0];
    const float* W_h0 = (const float*)d_in[1];
    const float* b_h0 = (const float*)d_in[2];
    const float* W_c0 = (const float*)d_in[3];
    const float* b_c0 = (const float*)d_in[4];
    const float* W_ih = (const float*)d_in[5];
    const float* W_hh = (const float*)d_in[6];
    const float* b_ih = (const float*)d_in[7];
    const float* b_hh = (const float*)d_in[8];
    float* out = (float*)d_out;

    (void)d_ws; (void)ws_size;  // no workspace, no LDS, no barriers

    hipLaunchKernelGGL(lstm_rowwise, dim3(BTOT / 64), dim3(64), 0, stream,
                       x, W_h0, b_h0, W_c0, b_c0, W_ih, W_hh, b_ih, b_hh, out);
}

// Round 8
// 136.594 us; speedup vs baseline: 3.4985x; 3.4985x over previous
//
#include <hip/hip_runtime.h>
#include <math.h>

#define BTOT   32768
#define LAT    128
#define H      17
#define G4     68      // 4*H
#define TSTEPS 50
#define NPR    102     // projection rows: 68 (W_ih) + 17 (W_h0) + 17 (W_c0)
#define WPAD   72      // Wbuf row pad (floats), XOR-swizzled

#define NW     8              // waves per block
#define RPW    3              // rows per wave (51 active lanes of 64)
#define RPB    (NW * RPW)     // 24 rows per block
#define TPB    (NW * 64)      // 512 threads

// fast gates: v_exp_f32 / v_rcp_f32 based, saturating-safe.
__device__ __forceinline__ float fsigmoid(float x) {
    float e = __expf(-x);                        // mul(-log2e) + v_exp
    return __builtin_amdgcn_rcpf(1.0f + e);      // add + v_rcp
}
// tanh(x) = 1 - 2*rcp(exp(2x)+1). x->+inf: exp->inf, rcp->0, ->1.
// x->-inf: exp->0, rcp(1)=1, ->-1. No abs/copysign/divide needed.
__device__ __forceinline__ float ftanhf(float x) {
    float e = __expf(2.0f * x);
    float t = __builtin_amdgcn_rcpf(e + 1.0f);
    return fmaf(-2.0f, t, 1.0f);
}

// R8 = R6 structure (wave-local rows, zero-barrier T-loop) with the AGPR
// banking defect fixed: the 68 W_hh values are consumed through inline-asm
// v_fmac_f32 whose "v" constraints force VGPR residency at EVERY use
// (R6 evidence: VGPR_Count=52 => W lived in AGPRs, +1 v_accvgpr_read per FMA).
#define FMAC(acc, w, h) asm("v_fmac_f32 %0, %1, %2" : "+v"(acc) : "v"(w), "v"(h))

__global__ __launch_bounds__(TPB, 4)
void lstm_fused(const float* __restrict__ x,
                const float* __restrict__ W_h0, const float* __restrict__ b_h0,
                const float* __restrict__ W_c0, const float* __restrict__ b_c0,
                const float* __restrict__ W_ih, const float* __restrict__ W_hh,
                const float* __restrict__ b_ih, const float* __restrict__ b_hh,
                float* __restrict__ out)
{
    __shared__ float x_tile[RPB][132];      // 12.7 KB
    __shared__ float Wbuf[NPR][WPAD];       // 29.4 KB (one k-half, swizzled)
    __shared__ float Wl[G4 * H];            //  4.6 KB (W_hh)
    __shared__ float hbuf[NW][RPW][20];     //  1.9 KB (wave-private h rows)

    const int t    = threadIdx.x;
    const int w    = t >> 6;
    const int lane = t & 63;
    const bool active = lane < RPW * H;       // 51
    const int rl = active ? (lane / H) : 0;   // 0..2
    const int j  = active ? (lane % H) : 0;   // 0..16
    const int r  = w * RPW + rl;              // 0..23
    const int grow0 = blockIdx.x * RPB;
    int grow = grow0 + r;
    const bool valid = active && (grow < BTOT);
    if (grow >= BTOT) grow = BTOT - 1;

    // ---- stage x tile (rows clamped) + W_hh; all 512 threads ----
    for (int i = t; i < RPB * 32; i += TPB) {              // 32 float4 per row
        int rr = i >> 5, c = i & 31;
        int gr = grow0 + rr; if (gr >= BTOT) gr = BTOT - 1;
        *(float4*)&x_tile[rr][c * 4] = ((const float4*)(x + (size_t)gr * LAT))[c];
    }
    for (int i = t; i < G4 * H; i += TPB) Wl[i] = W_hh[i];

    // ---- phase 1: projections, two k-halves of 64 ----
    float acc[6] = {0.f, 0.f, 0.f, 0.f, 0.f, 0.f};         // i,f,g,o, h0, c0
    for (int kh = 0; kh < 2; ++kh) {
        __syncthreads();  // kh=0: x_tile/Wl ready; kh=1: WAR on Wbuf
        for (int i = t; i < NPR * 16; i += TPB) {          // 16 float4 per half-row
            int row = i >> 4, c4 = (i & 15) * 4;
            const float* src = (row < G4) ? (W_ih + row * LAT)
                             : (row < 85) ? (W_h0 + (row - G4) * LAT)
                                          : (W_c0 + (row - 85) * LAT);
            float4 v = *(const float4*)(src + kh * 64 + c4);
            *(float4*)&Wbuf[row][c4 ^ (((row >> 3) & 1) << 2)] = v;  // swizzled store
        }
        __syncthreads();  // Wbuf half ready

        const int rows6[6] = { j, 17 + j, 34 + j, 51 + j, 68 + j, 85 + j };
        for (int kb = 0; kb < 16; ++kb) {
            float4 xv = *(const float4*)&x_tile[r][kh * 64 + kb * 4];
#pragma unroll
            for (int s = 0; s < 6; ++s) {
                const int row = rows6[s];
                float4 wv = *(const float4*)&Wbuf[row][(kb * 4) ^ (((row >> 3) & 1) << 2)];
                acc[s] = fmaf(xv.x, wv.x, acc[s]);
                acc[s] = fmaf(xv.y, wv.y, acc[s]);
                acc[s] = fmaf(xv.z, wv.z, acc[s]);
                acc[s] = fmaf(xv.w, wv.w, acc[s]);
            }
        }
    }

    const float xgi = acc[0] + b_ih[j]      + b_hh[j];
    const float xgf = acc[1] + b_ih[17 + j] + b_hh[17 + j];
    const float xgg = acc[2] + b_ih[34 + j] + b_hh[34 + j];
    const float xgo = acc[3] + b_ih[51 + j] + b_hh[51 + j];
    float h = acc[4] + b_h0[j];
    float c = acc[5] + b_c0[j];

    // ---- W_hh rows for gates i,f,g,o of element j -> VGPRs (pinned) ----
    float Wi[H], Wf[H], Wg[H], Wo[H];
#pragma unroll
    for (int k = 0; k < H; ++k) {
        Wi[k] = Wl[(0 * H + j) * H + k];
        Wf[k] = Wl[(1 * H + j) * H + k];
        Wg[k] = Wl[(2 * H + j) * H + k];
        Wo[k] = Wl[(3 * H + j) * H + k];
        asm volatile("" : "+v"(Wi[k]), "+v"(Wf[k]), "+v"(Wg[k]), "+v"(Wo[k]));
    }

    // ---- phase 2: 50-step recurrence, NO barriers (rows are wave-local) ----
    float* orow = out + (size_t)grow * (TSTEPS * H) + j;
    for (int tt = 0; tt < TSTEPS; ++tt) {
        if (active) hbuf[w][rl][j] = h;
        // same-wave write->read on hbuf: compiler inserts lgkmcnt wait

        float ai = xgi, af = xgf, ag = xgg, ao = xgo;
#pragma unroll
        for (int q = 0; q < 4; ++q) {
            float4 h4 = *(const float4*)&hbuf[w][rl][q * 4];
            FMAC(ai, Wi[q * 4 + 0], h4.x);
            FMAC(af, Wf[q * 4 + 0], h4.x);
            FMAC(ag, Wg[q * 4 + 0], h4.x);
            FMAC(ao, Wo[q * 4 + 0], h4.x);
            FMAC(ai, Wi[q * 4 + 1], h4.y);
            FMAC(af, Wf[q * 4 + 1], h4.y);
            FMAC(ag, Wg[q * 4 + 1], h4.y);
            FMAC(ao, Wo[q * 4 + 1], h4.y);
            FMAC(ai, Wi[q * 4 + 2], h4.z);
            FMAC(af, Wf[q * 4 + 2], h4.z);
            FMAC(ag, Wg[q * 4 + 2], h4.z);
            FMAC(ao, Wo[q * 4 + 2], h4.z);
            FMAC(ai, Wi[q * 4 + 3], h4.w);
            FMAC(af, Wf[q * 4 + 3], h4.w);
            FMAC(ag, Wg[q * 4 + 3], h4.w);
            FMAC(ao, Wo[q * 4 + 3], h4.w);
        }
        {
            const float hk = hbuf[w][rl][16];
            FMAC(ai, Wi[16], hk);
            FMAC(af, Wf[16], hk);
            FMAC(ag, Wg[16], hk);
            FMAC(ao, Wo[16], hk);
        }

        const float ig = fsigmoid(ai);
        const float fg = fsigmoid(af);
        const float gv = ftanhf(ag);
        const float og = fsigmoid(ao);
        c = fmaf(fg, c, ig * gv);
        h = og * ftanhf(c);

        if (valid) orow[tt * H] = h;
    }
}

extern "C" void kernel_launch(void* const* d_in, const int* in_sizes, int n_in,
                              void* d_out, int out_size, void* d_ws, size_t ws_size,
                              hipStream_t stream)
{
    const float* x    = (const float*)d_in[0];
    const float* W_h0 = (const float*)d_in[1];
    const float* b_h0 = (const float*)d_in[2];
    const float* W_c0 = (const float*)d_in[3];
    const float* b_c0 = (const float*)d_in[4];
    const float* W_ih = (const float*)d_in[5];
    const float* W_hh = (const float*)d_in[6];
    const float* b_ih = (const float*)d_in[7];
    const float* b_hh = (const float*)d_in[8];
    float* out = (float*)d_out;

    (void)d_ws; (void)ws_size;  // no workspace used

    const int nblk = (BTOT + RPB - 1) / RPB;   // 1366
    hipLaunchKernelGGL(lstm_fused, dim3(nblk), dim3(TPB), 0, stream,
                       x, W_h0, b_h0, W_c0, b_c0, W_ih, W_hh, b_ih, b_hh, out);
}